// Round 14
// baseline (1609.388 us; speedup 1.0000x reference)
//
#include <hip/hip_runtime.h>
#include <hip/hip_bf16.h>
#include <math.h>

#define DIM 1024
#define NE  64
#define BM  64
#define NT  32                    // 1024/32 k-tiles
// fast kernel LDS: ABr f32 [0,16384) (A 8K | Br 8K); Bu1 bf16 planes [16384,65536)
#define BU1B 16384
// safe kernel LDS (R13): [2][A 8K | Br 8K] dbuf + Bu1 f32 32KB
#define HALF_BYTES 16384
#define SBU1_BASE  32768
#define WS_NEED 1572864           // 3 planes * 262144 * 2B

typedef __attribute__((ext_vector_type(8))) short short8;
typedef __attribute__((ext_vector_type(4))) short short4v;
typedef __attribute__((ext_vector_type(4))) float f32x4;

__device__ __forceinline__ void gload16(const void* gptr, void* lptr) {
  __builtin_amdgcn_global_load_lds(
      (const __attribute__((address_space(1))) unsigned int*)(unsigned long long)gptr,
      (__attribute__((address_space(3))) unsigned int*)(unsigned int)(unsigned long long)lptr,
      16, 0, 0);
}

// 3-term bf16 split (RNE): f = h + m + l + O(2^-27 |f|)
__device__ __forceinline__ void bsplit(float f, unsigned short& h,
                                       unsigned short& m, unsigned short& l) {
  __hip_bfloat16 bh = __float2bfloat16(f);
  float r1 = f - __bfloat162float(bh);
  __hip_bfloat16 bm = __float2bfloat16(r1);
  __hip_bfloat16 bl = __float2bfloat16(r1 - __bfloat162float(bm));
  h = *reinterpret_cast<unsigned short*>(&bh);
  m = *reinterpret_cast<unsigned short*>(&bm);
  l = *reinterpret_cast<unsigned short*>(&bl);
}

// ---- prepass: split Wu1 [256][1024] into 3 bf16 planes in d_ws ----
__global__ __launch_bounds__(256)
void split_w(const float* __restrict__ Wu1, unsigned short* __restrict__ ws) {
  int idx = blockIdx.x * 256 + threadIdx.x;   // 0..262143
  float v = Wu1[idx];
  unsigned short h, m, l;
  bsplit(v, h, m, l);
  ws[idx] = h;
  ws[262144 + idx] = m;
  ws[524288 + idx] = l;
}

// ============================= FAST PATH =============================
__global__ __launch_bounds__(512)
void ur_fast(const float* __restrict__ hs,    // [M,1024]
             const float* __restrict__ Wr,    // [64,1024]
             const float* __restrict__ br,    // [64]
             const float* __restrict__ bu1,   // [256]
             const float* __restrict__ Wu2,   // [256]
             const float* __restrict__ bu2,   // [1]
             const unsigned short* __restrict__ wsp,  // 3 bf16 planes [256][1024]
             float* __restrict__ out,         // w[4M] | idx[4M] | k[M]
             int M) {
  __shared__ __align__(16) char smem[65536];

  const int tid = threadIdx.x;
  const int m0 = blockIdx.x * BM;
  const int w2 = tid >> 6, l = tid & 63;
  const int g = l >> 4, c = l & 15;
  const int rcol = 8 * w2 + (l & 7);          // router col (disjoint per wave)
  const int jb = l >> 3;                      // router token base
  const unsigned swc = (unsigned)((c >> 1) & 3);

  // ---- ABr staging (f32): LDS[row][q] = src[row][q ^ (row&7)], linear dest ----
  const int t8 = tid >> 3, k8 = tid & 7;
  const int kx = k8 ^ (t8 & 7);
  const char* pA  = (const char*)hs + (size_t)(m0 + t8) * 4096 + (kx << 4);
  const char* pBr = (const char*)Wr + (size_t)t8 * 4096 + (kx << 4);
  // ---- Bu1 plane staging: LDS slot u holds global chunk u ^ ((row>>1)&3) ----
  const unsigned ub = (unsigned)((tid & 3) ^ ((tid >> 3) & 3));
  const char* pBu = (const char*)wsp + (size_t)(tid >> 2) * 2048 + (ub << 4);
  const unsigned wb = (unsigned)(tid & ~63) * 16u;

  // A-plane writer constants: thread owns A[tok][4k] at f32 chunk kqg
  const int tok = tid >> 3;
  const int kqg = (tid & 7) ^ (tok & 7);
  const unsigned wbyte = (unsigned)(tok * 64 + (((kqg >> 1) ^ ((tid >> 4) & 3)) << 4)
                                    + ((kqg & 1) << 3));

  float ar[8];
#pragma unroll
  for (int j = 0; j < 8; ++j) ar[j] = 0.f;
  f32x4 acc[4][2];
#pragma unroll
  for (int s = 0; s < 4; ++s)
#pragma unroll
    for (int n = 0; n < 2; ++n) acc[s][n] = (f32x4){0.f, 0.f, 0.f, 0.f};

  // prologue: ABr(0)
  gload16(pA, smem + wb);
  gload16(pBr, smem + 8192 + wb);

#pragma unroll 1
  for (int t = 0; t < NT; ++t) {
    // Bu1 planes(t): 6 issues (48 KB); region free since MFMA(t-1) ended
#pragma unroll
    for (int li = 0; li < 6; ++li)
      gload16(pBu + (size_t)li * 262144, smem + (BU1B + li * 8192 + wb));

    asm volatile("s_waitcnt vmcnt(6)" ::: "memory");   // ABr(t) resident
    __builtin_amdgcn_s_barrier();
    __builtin_amdgcn_sched_barrier(0);

    // ---- phase 1: own-A chunk + router (fp32 VALU, R13-identical) ----
    const f32x4 a4 = *reinterpret_cast<const f32x4*>(smem + tid * 16);
#pragma unroll
    for (int kq = 0; kq < 8; ++kq) {
      const char* ab = smem + jb * 128 + (((unsigned)(kq ^ jb)) << 4);
      const f32x4 bv = *reinterpret_cast<const f32x4*>(
          smem + 8192 + rcol * 128 + (((unsigned)(kq ^ (l & 7))) << 4));
#pragma unroll
      for (int j = 0; j < 8; ++j) {
        const f32x4 av = *reinterpret_cast<const f32x4*>(ab + j * 1024);
        ar[j] = fmaf(av[0], bv[0], ar[j]);
        ar[j] = fmaf(av[1], bv[1], ar[j]);
        ar[j] = fmaf(av[2], bv[2], ar[j]);
        ar[j] = fmaf(av[3], bv[3], ar[j]);
      }
    }
    asm volatile("s_waitcnt lgkmcnt(0)" ::: "memory");  // all f32 reads done
    __builtin_amdgcn_s_barrier();                       // ABr region now dead

    // ---- cooperative A-split: 4 values -> 3 plane writes (8B each) ----
    {
      unsigned short hh[4], mm[4], ll[4];
#pragma unroll
      for (int e = 0; e < 4; ++e) bsplit(a4[e], hh[e], mm[e], ll[e]);
      short4v hv, mv, lv;
#pragma unroll
      for (int e = 0; e < 4; ++e) {
        hv[e] = (short)hh[e]; mv[e] = (short)mm[e]; lv[e] = (short)ll[e];
      }
      *reinterpret_cast<short4v*>(smem + wbyte) = hv;
      *reinterpret_cast<short4v*>(smem + 4096 + wbyte) = mv;
      *reinterpret_cast<short4v*>(smem + 8192 + wbyte) = lv;
    }
    asm volatile("s_waitcnt vmcnt(0) lgkmcnt(0)" ::: "memory");  // Bu1 + writes
    __builtin_amdgcn_s_barrier();
    __builtin_amdgcn_sched_barrier(0);

    // ---- MFMA phase: direct bf16 fragment reads, 6 products ----
    short8 Bh[2], Bm[2], Bl[2];
#pragma unroll
    for (int n = 0; n < 2; ++n) {
      const int qd = 32 * w2 + 16 * n + c;
      const char* bb = smem + BU1B + qd * 64 + (((unsigned)g ^ swc) << 4);
      Bh[n] = *reinterpret_cast<const short8*>(bb);
      Bm[n] = *reinterpret_cast<const short8*>(bb + 16384);
      Bl[n] = *reinterpret_cast<const short8*>(bb + 32768);
    }
#pragma unroll
    for (int s = 0; s < 4; ++s) {
      const char* aa = smem + (16 * s + c) * 64 + (((unsigned)g ^ swc) << 4);
      const short8 Ah = *reinterpret_cast<const short8*>(aa);
      const short8 Am = *reinterpret_cast<const short8*>(aa + 4096);
      const short8 Al = *reinterpret_cast<const short8*>(aa + 8192);
#pragma unroll
      for (int n = 0; n < 2; ++n) {
        acc[s][n] = __builtin_amdgcn_mfma_f32_16x16x32_bf16(Al, Bh[n], acc[s][n], 0, 0, 0);
        acc[s][n] = __builtin_amdgcn_mfma_f32_16x16x32_bf16(Ah, Bl[n], acc[s][n], 0, 0, 0);
        acc[s][n] = __builtin_amdgcn_mfma_f32_16x16x32_bf16(Am, Bm[n], acc[s][n], 0, 0, 0);
        acc[s][n] = __builtin_amdgcn_mfma_f32_16x16x32_bf16(Am, Bh[n], acc[s][n], 0, 0, 0);
        acc[s][n] = __builtin_amdgcn_mfma_f32_16x16x32_bf16(Ah, Bm[n], acc[s][n], 0, 0, 0);
        acc[s][n] = __builtin_amdgcn_mfma_f32_16x16x32_bf16(Ah, Bh[n], acc[s][n], 0, 0, 0);
      }
    }
    __builtin_amdgcn_s_barrier();   // planes + Bu1 readers done

    if (t != NT - 1) {              // ABr(t+1) into now-dead region
      pA += 128; pBr += 128; pBu += 64;
      gload16(pA, smem + wb);
      gload16(pBr, smem + 8192 + wb);
    }
  }
  __syncthreads();   // drains everything; overlay epilogue arrays

  // ---- epilogue (R13-identical) ----
  float* Lg = reinterpret_cast<float*>(smem);                 // [64][65]
  float* Xp = reinterpret_cast<float*>(smem + 16640);         // [128][65]
  float* Xs = reinterpret_cast<float*>(smem + 49920);         // [64]

  {
    const float bias = br[rcol];
#pragma unroll
    for (int j = 0; j < 8; ++j) Lg[(jb + 8 * j) * 65 + rcol] = ar[j] + bias;
  }

  float xp[4][4];
#pragma unroll
  for (int s = 0; s < 4; ++s)
#pragma unroll
    for (int reg = 0; reg < 4; ++reg) xp[s][reg] = 0.f;
#pragma unroll
  for (int n = 0; n < 2; ++n) {
    const int qd = 32 * w2 + 16 * n + c;
    const float w2f = Wu2[qd];
    const float b1 = bu1[qd];
#pragma unroll
    for (int s = 0; s < 4; ++s)
#pragma unroll
      for (int reg = 0; reg < 4; ++reg) {
        float h = acc[s][n][reg] + b1;
        float ge = 0.5f * h * (1.f + erff(h * 0.70710678118654752440f));
        xp[s][reg] = fmaf(ge, w2f, xp[s][reg]);
      }
  }
#pragma unroll
  for (int s = 0; s < 4; ++s)
#pragma unroll
    for (int reg = 0; reg < 4; ++reg)
      Xp[(w2 * 16 + c) * 65 + 16 * s + 4 * g + reg] = xp[s][reg];
  __syncthreads();

  if (tid < BM) {
    float x = bu2[0];
#pragma unroll
    for (int cc = 0; cc < 128; ++cc) x += Xp[cc * 65 + tid];
    Xs[tid] = x;
  }
  __syncthreads();

  const size_t Moff_i = 4 * (size_t)M;
  const size_t Moff_k = 8 * (size_t)M;

  for (int t = w2; t < BM; t += 8) {
    float cur = Lg[t * 65 + l];
    float topv[4];
    int topi[4];
#pragma unroll
    for (int s = 0; s < 4; ++s) {
      float mv = cur;
      int mi = l;
#pragma unroll
      for (int off = 32; off >= 1; off >>= 1) {
        float ov = __shfl_xor(mv, off, 64);
        int oi = __shfl_xor(mi, off, 64);
        if (ov > mv || (ov == mv && oi < mi)) { mv = ov; mi = oi; }
      }
      topv[s] = mv;
      topi[s] = mi;
      if (l == mi) cur = -INFINITY;
    }
    if (l == 0) {
      const int token = m0 + t;
      float x = Xs[t];
      float u = 1.f / (1.f + expf(-x));
      float kf = fmaf(3.f, u, 1.f);
      int kv = (int)rintf(kf);
      kv = kv < 1 ? 1 : (kv > 4 ? 4 : kv);
      float wv[4];
#pragma unroll
      for (int s = 0; s < 4; ++s) wv[s] = (s < kv) ? topv[s] : 0.f;
      float mx = fmaxf(fmaxf(wv[0], wv[1]), fmaxf(wv[2], wv[3]));
      float e[4], sum = 0.f;
#pragma unroll
      for (int s = 0; s < 4; ++s) { e[s] = expf(wv[s] - mx); sum += e[s]; }
      float inv = 1.f / sum;
#pragma unroll
      for (int s = 0; s < 4; ++s) {
        out[(size_t)token * 4 + s] = e[s] * inv;
        out[Moff_i + (size_t)token * 4 + s] = (s < kv) ? (float)topi[s] : -1.0f;
      }
      out[Moff_k + token] = (float)kv;
    }
  }
}

// ===================== SAFE FALLBACK (R13 verbatim) =====================
__global__ __launch_bounds__(512)
void ur_safe(const float* __restrict__ hs, const float* __restrict__ Wr,
             const float* __restrict__ br, const float* __restrict__ Wu1,
             const float* __restrict__ bu1, const float* __restrict__ Wu2,
             const float* __restrict__ bu2, float* __restrict__ out, int M) {
  __shared__ __align__(16) char smem[65536];
  const int tid = threadIdx.x;
  const int m0 = blockIdx.x * BM;
  const int w2 = tid >> 6, l = tid & 63;
  const int g = l >> 4, c = l & 15;
  const int rcol = 8 * w2 + (l & 7);
  const int jb = l >> 3;
  const int t8 = tid >> 3, k8 = tid & 7;
  const int kx = k8 ^ (t8 & 7);
  const char* pA  = (const char*)hs  + (size_t)(m0 + t8) * 4096 + (kx << 4);
  const char* pBr = (const char*)Wr  + (size_t)t8 * 4096 + (kx << 4);
  const char* pBu = (const char*)Wu1 + (size_t)t8 * 4096 + (kx << 4);
  const unsigned wb = (unsigned)(tid & ~63) * 16u;
  const unsigned axk0 = (unsigned)(((2 * g) ^ (c & 7)) << 4);
  const unsigned axk1 = (unsigned)(((2 * g + 1) ^ (c & 7)) << 4);
  float ar[8];
#pragma unroll
  for (int j = 0; j < 8; ++j) ar[j] = 0.f;
  f32x4 am_[4][2];
#pragma unroll
  for (int s = 0; s < 4; ++s)
#pragma unroll
    for (int n = 0; n < 2; ++n) am_[s][n] = (f32x4){0.f, 0.f, 0.f, 0.f};
  gload16(pA, smem + wb);
  gload16(pBr, smem + 8192 + wb);
  unsigned half = 0;
#pragma unroll 1
  for (int t = 0; t < NT; ++t) {
#pragma unroll
    for (int li = 0; li < 4; ++li)
      gload16(pBu + (size_t)li * 262144, smem + (SBU1_BASE + li * 8192 + wb));
    const unsigned oh = half ^ HALF_BYTES;
    if (t != NT - 1) { pA += 128; pBr += 128; pBu += 128; }
    gload16(pA, smem + oh + wb);
    gload16(pBr, smem + (oh + 8192 + wb));
    asm volatile("s_waitcnt vmcnt(6)" ::: "memory");
    __builtin_amdgcn_s_barrier();
    __builtin_amdgcn_sched_barrier(0);
    const char* hb = smem + half;
#pragma unroll
    for (int kq = 0; kq < 8; ++kq) {
      const char* ab = hb + jb * 128 + (((unsigned)(kq ^ jb)) << 4);
      const f32x4 bv = *reinterpret_cast<const f32x4*>(
          hb + 8192 + rcol * 128 + (((unsigned)(kq ^ (l & 7))) << 4));
#pragma unroll
      for (int j = 0; j < 8; ++j) {
        const f32x4 av = *reinterpret_cast<const f32x4*>(ab + j * 1024);
        ar[j] = fmaf(av[0], bv[0], ar[j]);
        ar[j] = fmaf(av[1], bv[1], ar[j]);
        ar[j] = fmaf(av[2], bv[2], ar[j]);
        ar[j] = fmaf(av[3], bv[3], ar[j]);
      }
    }
    asm volatile("s_waitcnt vmcnt(2)" ::: "memory");
    __builtin_amdgcn_s_barrier();
    __builtin_amdgcn_sched_barrier(0);
    short8 Bh[2], Bm[2], Bl[2];
#pragma unroll
    for (int n = 0; n < 2; ++n) {
      const char* bp = smem + SBU1_BASE + w2 * 4096 + n * 2048 + c * 128;
      const f32x4 u0 = *reinterpret_cast<const f32x4*>(bp + axk0);
      const f32x4 u1v = *reinterpret_cast<const f32x4*>(bp + axk1);
#pragma unroll
      for (int e = 0; e < 4; ++e) {
        unsigned short h, m, lo;
        bsplit(u0[e], h, m, lo);
        Bh[n][e] = (short)h; Bm[n][e] = (short)m; Bl[n][e] = (short)lo;
        bsplit(u1v[e], h, m, lo);
        Bh[n][4 + e] = (short)h; Bm[n][4 + e] = (short)m; Bl[n][4 + e] = (short)lo;
      }
    }
#pragma unroll
    for (int s = 0; s < 4; ++s) {
      const f32x4 v0 = *reinterpret_cast<const f32x4*>(hb + c * 128 + s * 2048 + axk0);
      const f32x4 v1 = *reinterpret_cast<const f32x4*>(hb + c * 128 + s * 2048 + axk1);
      short8 Ah, Am, Al;
#pragma unroll
      for (int e = 0; e < 4; ++e) {
        unsigned short h, m, lo;
        bsplit(v0[e], h, m, lo);
        Ah[e] = (short)h; Am[e] = (short)m; Al[e] = (short)lo;
        bsplit(v1[e], h, m, lo);
        Ah[4 + e] = (short)h; Am[4 + e] = (short)m; Al[4 + e] = (short)lo;
      }
#pragma unroll
      for (int n = 0; n < 2; ++n) {
        am_[s][n] = __builtin_amdgcn_mfma_f32_16x16x32_bf16(Al, Bh[n], am_[s][n], 0, 0, 0);
        am_[s][n] = __builtin_amdgcn_mfma_f32_16x16x32_bf16(Ah, Bl[n], am_[s][n], 0, 0, 0);
        am_[s][n] = __builtin_amdgcn_mfma_f32_16x16x32_bf16(Am, Bm[n], am_[s][n], 0, 0, 0);
        am_[s][n] = __builtin_amdgcn_mfma_f32_16x16x32_bf16(Am, Bh[n], am_[s][n], 0, 0, 0);
        am_[s][n] = __builtin_amdgcn_mfma_f32_16x16x32_bf16(Ah, Bm[n], am_[s][n], 0, 0, 0);
        am_[s][n] = __builtin_amdgcn_mfma_f32_16x16x32_bf16(Ah, Bh[n], am_[s][n], 0, 0, 0);
      }
    }
    __builtin_amdgcn_s_barrier();
    half = oh;
  }
  __syncthreads();
  float* Lg = reinterpret_cast<float*>(smem);
  float* Xp = reinterpret_cast<float*>(smem + 16640);
  float* Xs = reinterpret_cast<float*>(smem + 49920);
  {
    const float bias = br[rcol];
#pragma unroll
    for (int j = 0; j < 8; ++j) Lg[(jb + 8 * j) * 65 + rcol] = ar[j] + bias;
  }
  float xp[4][4];
#pragma unroll
  for (int s = 0; s < 4; ++s)
#pragma unroll
    for (int reg = 0; reg < 4; ++reg) xp[s][reg] = 0.f;
#pragma unroll
  for (int n = 0; n < 2; ++n) {
    const int qd = 32 * w2 + 16 * n + c;
    const float w2f = Wu2[qd];
    const float b1 = bu1[qd];
#pragma unroll
    for (int s = 0; s < 4; ++s)
#pragma unroll
      for (int reg = 0; reg < 4; ++reg) {
        float h = am_[s][n][reg] + b1;
        float ge = 0.5f * h * (1.f + erff(h * 0.70710678118654752440f));
        xp[s][reg] = fmaf(ge, w2f, xp[s][reg]);
      }
  }
#pragma unroll
  for (int s = 0; s < 4; ++s)
#pragma unroll
    for (int reg = 0; reg < 4; ++reg)
      Xp[(w2 * 16 + c) * 65 + 16 * s + 4 * g + reg] = xp[s][reg];
  __syncthreads();
  if (tid < BM) {
    float x = bu2[0];
#pragma unroll
    for (int cc = 0; cc < 128; ++cc) x += Xp[cc * 65 + tid];
    Xs[tid] = x;
  }
  __syncthreads();
  const size_t Moff_i = 4 * (size_t)M;
  const size_t Moff_k = 8 * (size_t)M;
  for (int t = w2; t < BM; t += 8) {
    float cur = Lg[t * 65 + l];
    float topv[4];
    int topi[4];
#pragma unroll
    for (int s = 0; s < 4; ++s) {
      float mv = cur;
      int mi = l;
#pragma unroll
      for (int off = 32; off >= 1; off >>= 1) {
        float ov = __shfl_xor(mv, off, 64);
        int oi = __shfl_xor(mi, off, 64);
        if (ov > mv || (ov == mv && oi < mi)) { mv = ov; mi = oi; }
      }
      topv[s] = mv;
      topi[s] = mi;
      if (l == mi) cur = -INFINITY;
    }
    if (l == 0) {
      const int token = m0 + t;
      float x = Xs[t];
      float u = 1.f / (1.f + expf(-x));
      float kf = fmaf(3.f, u, 1.f);
      int kv = (int)rintf(kf);
      kv = kv < 1 ? 1 : (kv > 4 ? 4 : kv);
      float wv[4];
#pragma unroll
      for (int s = 0; s < 4; ++s) wv[s] = (s < kv) ? topv[s] : 0.f;
      float mx = fmaxf(fmaxf(wv[0], wv[1]), fmaxf(wv[2], wv[3]));
      float e[4], sum = 0.f;
#pragma unroll
      for (int s = 0; s < 4; ++s) { e[s] = expf(wv[s] - mx); sum += e[s]; }
      float inv = 1.f / sum;
#pragma unroll
      for (int s = 0; s < 4; ++s) {
        out[(size_t)token * 4 + s] = e[s] * inv;
        out[Moff_i + (size_t)token * 4 + s] = (s < kv) ? (float)topi[s] : -1.0f;
      }
      out[Moff_k + token] = (float)kv;
    }
  }
}

extern "C" void kernel_launch(void* const* d_in, const int* in_sizes, int n_in,
                              void* d_out, int out_size, void* d_ws, size_t ws_size,
                              hipStream_t stream) {
  (void)n_in; (void)out_size;
  const float* hs  = (const float*)d_in[0];
  const float* Wr  = (const float*)d_in[1];
  const float* br  = (const float*)d_in[2];
  const float* Wu1 = (const float*)d_in[3];
  const float* bu1 = (const float*)d_in[4];
  const float* Wu2 = (const float*)d_in[5];
  const float* bu2 = (const float*)d_in[6];
  float* out = (float*)d_out;

  const int M = in_sizes[0] / DIM;  // 32768

  if (ws_size >= (size_t)WS_NEED && d_ws != nullptr) {
    unsigned short* wsp = (unsigned short*)d_ws;
    hipLaunchKernelGGL(split_w, dim3(1024), dim3(256), 0, stream, Wu1, wsp);
    hipLaunchKernelGGL(ur_fast, dim3(M / BM), dim3(512), 0, stream,
                       hs, Wr, br, bu1, Wu2, bu2, wsp, out, M);
  } else {
    hipLaunchKernelGGL(ur_safe, dim3(M / BM), dim3(512), 0, stream,
                       hs, Wr, br, Wu1, bu1, Wu2, bu2, out, M);
  }
}

// Round 15
// 269.455 us; speedup vs baseline: 5.9728x; 5.9728x over previous
//
#include <hip/hip_runtime.h>
#include <hip/hip_bf16.h>
#include <math.h>

#define DIM 1024
#define NE  64
#define BM  64
#define NT  32                    // 1024/32 k-tiles
// LDS: [2][A 8KB | Br 8KB] dbuf + Bu1 f32 32KB = 64KB
#define HALF_BYTES 16384
#define BU1_BASE   32768
#define LDS_BYTES  65536

typedef __attribute__((ext_vector_type(8))) short short8;
typedef __attribute__((ext_vector_type(4))) float f32x4;

__device__ __forceinline__ void gload16(const void* gptr, void* lptr) {
  __builtin_amdgcn_global_load_lds(
      (const __attribute__((address_space(1))) unsigned int*)(unsigned long long)gptr,
      (__attribute__((address_space(3))) unsigned int*)(unsigned int)(unsigned long long)lptr,
      16, 0, 0);
}

// Truncation 3-term bf16 split: f == h + m + l EXACTLY (24-bit mantissa -> 3x8)
__device__ __forceinline__ void tsplit(float f, unsigned short& h,
                                       unsigned short& m, unsigned short& l) {
  unsigned fb = __float_as_uint(f);
  h = (unsigned short)(fb >> 16);
  float r1 = f - __uint_as_float(fb & 0xFFFF0000u);      // exact
  unsigned r1b = __float_as_uint(r1);
  m = (unsigned short)(r1b >> 16);
  float r2 = r1 - __uint_as_float(r1b & 0xFFFF0000u);    // exact, fits bf16
  l = (unsigned short)(__float_as_uint(r2) >> 16);
}

__global__ __launch_bounds__(512)
void ur_hyb(const float* __restrict__ hs,    // [M,1024]
            const float* __restrict__ Wr,    // [64,1024]
            const float* __restrict__ br,    // [64]
            const float* __restrict__ Wu1,   // [256,1024]
            const float* __restrict__ bu1,   // [256]
            const float* __restrict__ Wu2,   // [256]
            const float* __restrict__ bu2,   // [1]
            float* __restrict__ out,         // w[4M] | idx[4M] | k[M]
            int M) {
  __shared__ __align__(16) char smem[LDS_BYTES];

  const int tid = threadIdx.x;
  const int m0 = blockIdx.x * BM;
  const int w2 = tid >> 6, l = tid & 63;     // wave, lane
  const int g = l >> 4, c = l & 15;          // mfma fragment coords
  // router decomposition: 4 tokens x 2 cols per thread
  const int tg = tid >> 5;                   // 0..15 -> tokens 4tg..4tg+3
  const int rc = tid & 31;                   // cols rc, rc+32

  // ---- staging sources (R13-identical): LDS[row][q] = src[row][q ^ (row&7)] ----
  const int t8 = tid >> 3, k8 = tid & 7;
  const int kx = k8 ^ (t8 & 7);
  const char* pA  = (const char*)hs  + (size_t)(m0 + t8) * 4096 + (kx << 4);
  const char* pBr = (const char*)Wr  + (size_t)t8 * 4096 + (kx << 4);
  const char* pBu = (const char*)Wu1 + (size_t)t8 * 4096 + (kx << 4);
  const unsigned wb = (unsigned)(tid & ~63) * 16u;   // wave-uniform lane-0 part

  // fragment read offsets (R11-verified scheme; row&7 == c&7)
  const unsigned axk0 = (unsigned)(((2 * g) ^ (c & 7)) << 4);
  const unsigned axk1 = (unsigned)(((2 * g + 1) ^ (c & 7)) << 4);

  float ar[4][2];
#pragma unroll
  for (int j = 0; j < 4; ++j) { ar[j][0] = 0.f; ar[j][1] = 0.f; }
  f32x4 am_[4][2];
#pragma unroll
  for (int s = 0; s < 4; ++s)
#pragma unroll
    for (int n = 0; n < 2; ++n) am_[s][n] = (f32x4){0.f, 0.f, 0.f, 0.f};

  // ---- prologue: stage A/Br(0) into half 0 ----
  gload16(pA, smem + wb);
  gload16(pBr, smem + 8192 + wb);

  unsigned half = 0;
#pragma unroll 1
  for (int t = 0; t < NT; ++t) {
    // Bu1(t): 4 issues (prev readers done at last end-barrier)
#pragma unroll
    for (int li = 0; li < 4; ++li)
      gload16(pBu + (size_t)li * 262144, smem + (BU1_BASE + li * 8192 + wb));
    const unsigned oh = half ^ HALF_BYTES;
    if (t != NT - 1) { pA += 128; pBr += 128; pBu += 128; }
    gload16(pA, smem + oh + wb);
    gload16(pBr, smem + (oh + 8192 + wb));

    asm volatile("s_waitcnt vmcnt(6)" ::: "memory");  // A/Br(t) resident
    __builtin_amdgcn_s_barrier();
    __builtin_amdgcn_sched_barrier(0);

    // ---- phase 1: router fp32 VALU, 4 tok x 2 col (48 LDS reads/tile) ----
    const char* hb = smem + half;
#pragma unroll
    for (int kq = 0; kq < 8; ++kq) {
      f32x4 av[4];
#pragma unroll
      for (int j = 0; j < 4; ++j) {
        const int row = 4 * tg + j;
        av[j] = *reinterpret_cast<const f32x4*>(
            hb + row * 128 + (((unsigned)(kq ^ (row & 7))) << 4));
      }
#pragma unroll
      for (int n = 0; n < 2; ++n) {
        const int col = rc + 32 * n;
        const f32x4 bv = *reinterpret_cast<const f32x4*>(
            hb + 8192 + col * 128 + (((unsigned)(kq ^ (rc & 7))) << 4));
#pragma unroll
        for (int j = 0; j < 4; ++j) {
          ar[j][n] = fmaf(av[j][0], bv[0], ar[j][n]);
          ar[j][n] = fmaf(av[j][1], bv[1], ar[j][n]);
          ar[j][n] = fmaf(av[j][2], bv[2], ar[j][n]);
          ar[j][n] = fmaf(av[j][3], bv[3], ar[j][n]);
        }
      }
    }

    asm volatile("s_waitcnt vmcnt(2)" ::: "memory");   // Bu1(t) resident
    __builtin_amdgcn_s_barrier();
    __builtin_amdgcn_sched_barrier(0);

    // ---- phase 2: B splits (trunc-exact), then per-s A split + 8-product MFMA ----
    short8 Bh[2], Bm[2], Bl[2];
#pragma unroll
    for (int n = 0; n < 2; ++n) {
      const char* bp = smem + BU1_BASE + w2 * 4096 + n * 2048 + c * 128;
      const f32x4 u0 = *reinterpret_cast<const f32x4*>(bp + axk0);
      const f32x4 u1v = *reinterpret_cast<const f32x4*>(bp + axk1);
#pragma unroll
      for (int e = 0; e < 4; ++e) {
        unsigned short h, m, lo;
        tsplit(u0[e], h, m, lo);
        Bh[n][e] = (short)h; Bm[n][e] = (short)m; Bl[n][e] = (short)lo;
        tsplit(u1v[e], h, m, lo);
        Bh[n][4 + e] = (short)h; Bm[n][4 + e] = (short)m; Bl[n][4 + e] = (short)lo;
      }
    }
#pragma unroll
    for (int s = 0; s < 4; ++s) {
      const f32x4 v0 = *reinterpret_cast<const f32x4*>(hb + c * 128 + s * 2048 + axk0);
      const f32x4 v1 = *reinterpret_cast<const f32x4*>(hb + c * 128 + s * 2048 + axk1);
      short8 Ah, Am, Al;
#pragma unroll
      for (int e = 0; e < 4; ++e) {
        unsigned short h, m, lo;
        tsplit(v0[e], h, m, lo);
        Ah[e] = (short)h; Am[e] = (short)m; Al[e] = (short)lo;
        tsplit(v1[e], h, m, lo);
        Ah[4 + e] = (short)h; Am[4 + e] = (short)m; Al[4 + e] = (short)lo;
      }
#pragma unroll
      for (int n = 0; n < 2; ++n) {
        // 8 of 9 products (drop only ll ~ 2^-32): exact to fp32 class
        am_[s][n] = __builtin_amdgcn_mfma_f32_16x16x32_bf16(Al, Bm[n], am_[s][n], 0, 0, 0);
        am_[s][n] = __builtin_amdgcn_mfma_f32_16x16x32_bf16(Am, Bl[n], am_[s][n], 0, 0, 0);
        am_[s][n] = __builtin_amdgcn_mfma_f32_16x16x32_bf16(Al, Bh[n], am_[s][n], 0, 0, 0);
        am_[s][n] = __builtin_amdgcn_mfma_f32_16x16x32_bf16(Ah, Bl[n], am_[s][n], 0, 0, 0);
        am_[s][n] = __builtin_amdgcn_mfma_f32_16x16x32_bf16(Am, Bm[n], am_[s][n], 0, 0, 0);
        am_[s][n] = __builtin_amdgcn_mfma_f32_16x16x32_bf16(Am, Bh[n], am_[s][n], 0, 0, 0);
        am_[s][n] = __builtin_amdgcn_mfma_f32_16x16x32_bf16(Ah, Bm[n], am_[s][n], 0, 0, 0);
        am_[s][n] = __builtin_amdgcn_mfma_f32_16x16x32_bf16(Ah, Bh[n], am_[s][n], 0, 0, 0);
      }
    }

    __builtin_amdgcn_s_barrier();   // all readers of Bu1/half done
    half = oh;
  }
  __syncthreads();     // drains dangling loads; overlay safe

  // ---- epilogue ----
  float* Lg = reinterpret_cast<float*>(smem);                 // [64][65]
  float* Xp = reinterpret_cast<float*>(smem + 16640);         // [128][65]
  float* Xs = reinterpret_cast<float*>(smem + 49920);         // [64]

#pragma unroll
  for (int n = 0; n < 2; ++n) {
    const int col = rc + 32 * n;
    const float bias = br[col];
#pragma unroll
    for (int j = 0; j < 4; ++j) Lg[(4 * tg + j) * 65 + col] = ar[j][n] + bias;
  }

  // u1 -> GELU -> dot W_u2. C/D [m89, R11-verified]:
  // am_[s][n][reg] = h1[16s+4g+reg][32w2+16n+c]
  float xp[4][4];
#pragma unroll
  for (int s = 0; s < 4; ++s)
#pragma unroll
    for (int reg = 0; reg < 4; ++reg) xp[s][reg] = 0.f;
#pragma unroll
  for (int n = 0; n < 2; ++n) {
    const int qd = 32 * w2 + 16 * n + c;
    const float w2f = Wu2[qd];
    const float b1 = bu1[qd];
#pragma unroll
    for (int s = 0; s < 4; ++s)
#pragma unroll
      for (int reg = 0; reg < 4; ++reg) {
        float h = am_[s][n][reg] + b1;
        float ge = 0.5f * h * (1.f + erff(h * 0.70710678118654752440f));
        xp[s][reg] = fmaf(ge, w2f, xp[s][reg]);
      }
  }
#pragma unroll
  for (int s = 0; s < 4; ++s)
#pragma unroll
    for (int reg = 0; reg < 4; ++reg)
      Xp[(w2 * 16 + c) * 65 + 16 * s + 4 * g + reg] = xp[s][reg];
  __syncthreads();

  if (tid < BM) {
    float x = bu2[0];
#pragma unroll
    for (int cc = 0; cc < 128; ++cc) x += Xp[cc * 65 + tid];
    Xs[tid] = x;
  }
  __syncthreads();

  // ---- per-token top-4 + masked softmax: one wave per token ----
  const size_t Moff_i = 4 * (size_t)M;
  const size_t Moff_k = 8 * (size_t)M;

  for (int t = w2; t < BM; t += 8) {
    float cur = Lg[t * 65 + l];
    float topv[4];
    int topi[4];
#pragma unroll
    for (int s = 0; s < 4; ++s) {
      float mv = cur;
      int mi = l;
#pragma unroll
      for (int off = 32; off >= 1; off >>= 1) {
        float ov = __shfl_xor(mv, off, 64);
        int oi = __shfl_xor(mi, off, 64);
        if (ov > mv || (ov == mv && oi < mi)) { mv = ov; mi = oi; }
      }
      topv[s] = mv;
      topi[s] = mi;
      if (l == mi) cur = -INFINITY;        // stable: lowest index wins ties
    }
    if (l == 0) {
      const int token = m0 + t;
      float x = Xs[t];
      float u = 1.f / (1.f + expf(-x));
      float kf = fmaf(3.f, u, 1.f);
      int kv = (int)rintf(kf);             // round-half-even == jnp.round
      kv = kv < 1 ? 1 : (kv > 4 ? 4 : kv);

      float wv[4];
#pragma unroll
      for (int s = 0; s < 4; ++s) wv[s] = (s < kv) ? topv[s] : 0.f;
      float mx = fmaxf(fmaxf(wv[0], wv[1]), fmaxf(wv[2], wv[3]));
      float e[4], sum = 0.f;
#pragma unroll
      for (int s = 0; s < 4; ++s) { e[s] = expf(wv[s] - mx); sum += e[s]; }
      float inv = 1.f / sum;
#pragma unroll
      for (int s = 0; s < 4; ++s) {
        out[(size_t)token * 4 + s] = e[s] * inv;
        out[Moff_i + (size_t)token * 4 + s] = (s < kv) ? (float)topi[s] : -1.0f;
      }
      out[Moff_k + token] = (float)kv;
    }
  }
}

extern "C" void kernel_launch(void* const* d_in, const int* in_sizes, int n_in,
                              void* d_out, int out_size, void* d_ws, size_t ws_size,
                              hipStream_t stream) {
  (void)n_in; (void)d_ws; (void)ws_size; (void)out_size;
  const float* hs  = (const float*)d_in[0];
  const float* Wr  = (const float*)d_in[1];
  const float* br  = (const float*)d_in[2];
  const float* Wu1 = (const float*)d_in[3];
  const float* bu1 = (const float*)d_in[4];
  const float* Wu2 = (const float*)d_in[5];
  const float* bu2 = (const float*)d_in[6];
  float* out = (float*)d_out;

  const int M = in_sizes[0] / DIM;  // 32768
  dim3 grid(M / BM);                // 512 blocks, 64 KB LDS, 2 blocks/CU
  dim3 block(512);                  // 8 waves -> 4 waves/SIMD
  hipLaunchKernelGGL(ur_hyb, grid, block, 0, stream,
                     hs, Wr, br, Wu1, bu1, Wu2, bu2, out, M);
}

// Round 17
// 244.658 us; speedup vs baseline: 6.5781x; 1.1014x over previous
//
#include <hip/hip_runtime.h>
#include <hip/hip_bf16.h>
#include <math.h>

#define DIM 1024
#define NE  64
#define BM  64
#define NT  32                    // 1024/32 k-tiles
// LDS: [2][A 8KB | Br 8KB] dbuf + Bu1 f32 32KB = 64KB
#define HALF_BYTES 16384
#define BU1_BASE   32768
#define LDS_BYTES  65536

typedef __attribute__((ext_vector_type(8))) short short8;
typedef __attribute__((ext_vector_type(4))) float f32x4;
typedef __attribute__((ext_vector_type(4))) unsigned uint4v;

__device__ __forceinline__ void gload16(const void* gptr, void* lptr) {
  __builtin_amdgcn_global_load_lds(
      (const __attribute__((address_space(1))) unsigned int*)(unsigned long long)gptr,
      (__attribute__((address_space(3))) unsigned int*)(unsigned int)(unsigned long long)lptr,
      16, 0, 0);
}

// Paired truncation 3-term bf16 split: f == h + m + l EXACTLY per value.
// Produces packed bf16-pair u32s (low16 = f0, high16 = f1) via v_perm_b32.
struct Sp3 { unsigned h, m, l; };
__device__ __forceinline__ Sp3 tsplit2(float f0, float f1) {
  Sp3 r;
  unsigned a = __float_as_uint(f0), b = __float_as_uint(f1);
  r.h = __builtin_amdgcn_perm(b, a, 0x07060302);   // [hi16(f1) | hi16(f0)]
  float r0 = f0 - __uint_as_float(a & 0xFFFF0000u);    // exact
  float r1 = f1 - __uint_as_float(b & 0xFFFF0000u);
  unsigned ra = __float_as_uint(r0), rb = __float_as_uint(r1);
  r.m = __builtin_amdgcn_perm(rb, ra, 0x07060302);
  float s0 = r0 - __uint_as_float(ra & 0xFFFF0000u);   // exact, fits bf16
  float s1 = r1 - __uint_as_float(rb & 0xFFFF0000u);
  r.l = __builtin_amdgcn_perm(__float_as_uint(s1), __float_as_uint(s0), 0x07060302);
  return r;
}

__device__ __forceinline__ short8 as_s8(uint4v v) {
  return *reinterpret_cast<short8*>(&v);
}

__global__ __launch_bounds__(512)
void ur_hyb(const float* __restrict__ hs,    // [M,1024]
            const float* __restrict__ Wr,    // [64,1024]
            const float* __restrict__ br,    // [64]
            const float* __restrict__ Wu1,   // [256,1024]
            const float* __restrict__ bu1,   // [256]
            const float* __restrict__ Wu2,   // [256]
            const float* __restrict__ bu2,   // [1]
            float* __restrict__ out,         // w[4M] | idx[4M] | k[M]
            int M) {
  __shared__ __align__(16) char smem[LDS_BYTES];

  const int tid = threadIdx.x;
  const int m0 = blockIdx.x * BM;
  const int w2 = tid >> 6, l = tid & 63;     // wave, lane
  const int g = l >> 4, c = l & 15;          // mfma fragment coords
  // router decomposition: 4 tokens x 2 cols per thread
  const int tg = tid >> 5;                   // 0..15 -> tokens 4tg..4tg+3
  const int rc = tid & 31;                   // cols rc, rc+32

  // ---- staging sources (R13-identical): LDS[row][q] = src[row][q ^ (row&7)] ----
  const int t8 = tid >> 3, k8 = tid & 7;
  const int kx = k8 ^ (t8 & 7);
  const char* pA  = (const char*)hs  + (size_t)(m0 + t8) * 4096 + (kx << 4);
  const char* pBr = (const char*)Wr  + (size_t)t8 * 4096 + (kx << 4);
  const char* pBu = (const char*)Wu1 + (size_t)t8 * 4096 + (kx << 4);
  const unsigned wb = (unsigned)(tid & ~63) * 16u;   // wave-uniform lane-0 part

  // fragment read offsets (R11-verified scheme; row&7 == c&7)
  const unsigned axk0 = (unsigned)(((2 * g) ^ (c & 7)) << 4);
  const unsigned axk1 = (unsigned)(((2 * g + 1) ^ (c & 7)) << 4);

  float ar[4][2];
#pragma unroll
  for (int j = 0; j < 4; ++j) { ar[j][0] = 0.f; ar[j][1] = 0.f; }
  f32x4 am_[4][2];
#pragma unroll
  for (int s = 0; s < 4; ++s)
#pragma unroll
    for (int n = 0; n < 2; ++n) am_[s][n] = (f32x4){0.f, 0.f, 0.f, 0.f};

  // ---- prologue: stage A/Br(0) into half 0 ----
  gload16(pA, smem + wb);
  gload16(pBr, smem + 8192 + wb);

  unsigned half = 0;
#pragma unroll 1
  for (int t = 0; t < NT; ++t) {
    // Bu1(t): 4 issues (prev readers done at last end-barrier)
#pragma unroll
    for (int li = 0; li < 4; ++li)
      gload16(pBu + (size_t)li * 262144, smem + (BU1_BASE + li * 8192 + wb));
    const unsigned oh = half ^ HALF_BYTES;
    if (t != NT - 1) { pA += 128; pBr += 128; pBu += 128; }
    gload16(pA, smem + oh + wb);
    gload16(pBr, smem + (oh + 8192 + wb));

    asm volatile("s_waitcnt vmcnt(6)" ::: "memory");  // A/Br(t) resident
    __builtin_amdgcn_s_barrier();

    // ---- phase 1: router fp32 VALU, 4 tok x 2 col ----
    const char* hb = smem + half;
#pragma unroll
    for (int kq = 0; kq < 8; ++kq) {
      f32x4 av[4];
#pragma unroll
      for (int j = 0; j < 4; ++j) {
        const int row = 4 * tg + j;
        av[j] = *reinterpret_cast<const f32x4*>(
            hb + row * 128 + (((unsigned)(kq ^ (row & 7))) << 4));
      }
#pragma unroll
      for (int n = 0; n < 2; ++n) {
        const int col = rc + 32 * n;
        const f32x4 bv = *reinterpret_cast<const f32x4*>(
            hb + 8192 + col * 128 + (((unsigned)(kq ^ (rc & 7))) << 4));
#pragma unroll
        for (int j = 0; j < 4; ++j) {
          ar[j][n] = fmaf(av[j][0], bv[0], ar[j][n]);
          ar[j][n] = fmaf(av[j][1], bv[1], ar[j][n]);
          ar[j][n] = fmaf(av[j][2], bv[2], ar[j][n]);
          ar[j][n] = fmaf(av[j][3], bv[3], ar[j][n]);
        }
      }
    }

    asm volatile("s_waitcnt vmcnt(2)" ::: "memory");   // Bu1(t) resident
    __builtin_amdgcn_s_barrier();

    // ---- phase 2: B splits (perm-packed), then per-s A split + 8-product MFMA ----
    short8 Bh[2], Bm[2], Bl[2];
#pragma unroll
    for (int n = 0; n < 2; ++n) {
      const char* bp = smem + BU1_BASE + w2 * 4096 + n * 2048 + c * 128;
      const f32x4 u0 = *reinterpret_cast<const f32x4*>(bp + axk0);
      const f32x4 u1v = *reinterpret_cast<const f32x4*>(bp + axk1);
      uint4v hv, mv, lv;
      Sp3 p0 = tsplit2(u0[0], u0[1]);
      Sp3 p1 = tsplit2(u0[2], u0[3]);
      Sp3 p2 = tsplit2(u1v[0], u1v[1]);
      Sp3 p3 = tsplit2(u1v[2], u1v[3]);
      hv[0] = p0.h; mv[0] = p0.m; lv[0] = p0.l;
      hv[1] = p1.h; mv[1] = p1.m; lv[1] = p1.l;
      hv[2] = p2.h; mv[2] = p2.m; lv[2] = p2.l;
      hv[3] = p3.h; mv[3] = p3.m; lv[3] = p3.l;
      Bh[n] = as_s8(hv); Bm[n] = as_s8(mv); Bl[n] = as_s8(lv);
    }
#pragma unroll
    for (int s = 0; s < 4; ++s) {
      const f32x4 v0 = *reinterpret_cast<const f32x4*>(hb + c * 128 + s * 2048 + axk0);
      const f32x4 v1 = *reinterpret_cast<const f32x4*>(hb + c * 128 + s * 2048 + axk1);
      uint4v hv, mv, lv;
      Sp3 p0 = tsplit2(v0[0], v0[1]);
      Sp3 p1 = tsplit2(v0[2], v0[3]);
      Sp3 p2 = tsplit2(v1[0], v1[1]);
      Sp3 p3 = tsplit2(v1[2], v1[3]);
      hv[0] = p0.h; mv[0] = p0.m; lv[0] = p0.l;
      hv[1] = p1.h; mv[1] = p1.m; lv[1] = p1.l;
      hv[2] = p2.h; mv[2] = p2.m; lv[2] = p2.l;
      hv[3] = p3.h; mv[3] = p3.m; lv[3] = p3.l;
      const short8 Ah = as_s8(hv), Am = as_s8(mv), Al = as_s8(lv);
#pragma unroll
      for (int n = 0; n < 2; ++n) {
        // 8 of 9 products (drop only ll ~ 2^-32): exact to fp32 class
        am_[s][n] = __builtin_amdgcn_mfma_f32_16x16x32_bf16(Al, Bm[n], am_[s][n], 0, 0, 0);
        am_[s][n] = __builtin_amdgcn_mfma_f32_16x16x32_bf16(Am, Bl[n], am_[s][n], 0, 0, 0);
        am_[s][n] = __builtin_amdgcn_mfma_f32_16x16x32_bf16(Al, Bh[n], am_[s][n], 0, 0, 0);
        am_[s][n] = __builtin_amdgcn_mfma_f32_16x16x32_bf16(Ah, Bl[n], am_[s][n], 0, 0, 0);
        am_[s][n] = __builtin_amdgcn_mfma_f32_16x16x32_bf16(Am, Bm[n], am_[s][n], 0, 0, 0);
        am_[s][n] = __builtin_amdgcn_mfma_f32_16x16x32_bf16(Am, Bh[n], am_[s][n], 0, 0, 0);
        am_[s][n] = __builtin_amdgcn_mfma_f32_16x16x32_bf16(Ah, Bm[n], am_[s][n], 0, 0, 0);
        am_[s][n] = __builtin_amdgcn_mfma_f32_16x16x32_bf16(Ah, Bh[n], am_[s][n], 0, 0, 0);
      }
    }

    __builtin_amdgcn_s_barrier();   // all readers of Bu1/half done
    half = oh;
  }
  __syncthreads();     // drains dangling loads; overlay safe

  // ---- epilogue ----
  float* Lg = reinterpret_cast<float*>(smem);                 // [64][65]
  float* Xp = reinterpret_cast<float*>(smem + 16640);         // [128][65]
  float* Xs = reinterpret_cast<float*>(smem + 49920);         // [64]

#pragma unroll
  for (int n = 0; n < 2; ++n) {
    const int col = rc + 32 * n;
    const float bias = br[col];
#pragma unroll
    for (int j = 0; j < 4; ++j) Lg[(4 * tg + j) * 65 + col] = ar[j][n] + bias;
  }

  // u1 -> GELU -> dot W_u2. C/D [m89, R11-verified]:
  // am_[s][n][reg] = h1[16s+4g+reg][32w2+16n+c]
  float xp[4][4];
#pragma unroll
  for (int s = 0; s < 4; ++s)
#pragma unroll
    for (int reg = 0; reg < 4; ++reg) xp[s][reg] = 0.f;
#pragma unroll
  for (int n = 0; n < 2; ++n) {
    const int qd = 32 * w2 + 16 * n + c;
    const float w2f = Wu2[qd];
    const float b1 = bu1[qd];
#pragma unroll
    for (int s = 0; s < 4; ++s)
#pragma unroll
      for (int reg = 0; reg < 4; ++reg) {
        float h = am_[s][n][reg] + b1;
        float ge = 0.5f * h * (1.f + erff(h * 0.70710678118654752440f));
        xp[s][reg] = fmaf(ge, w2f, xp[s][reg]);
      }
  }
#pragma unroll
  for (int s = 0; s < 4; ++s)
#pragma unroll
    for (int reg = 0; reg < 4; ++reg)
      Xp[(w2 * 16 + c) * 65 + 16 * s + 4 * g + reg] = xp[s][reg];
  __syncthreads();

  if (tid < BM) {
    float x = bu2[0];
#pragma unroll
    for (int cc = 0; cc < 128; ++cc) x += Xp[cc * 65 + tid];
    Xs[tid] = x;
  }
  __syncthreads();

  // ---- per-token top-4 + masked softmax: one wave per token ----
  const size_t Moff_i = 4 * (size_t)M;
  const size_t Moff_k = 8 * (size_t)M;

  for (int t = w2; t < BM; t += 8) {
    float cur = Lg[t * 65 + l];
    float topv[4];
    int topi[4];
#pragma unroll
    for (int s = 0; s < 4; ++s) {
      float mv = cur;
      int mi = l;
#pragma unroll
      for (int off = 32; off >= 1; off >>= 1) {
        float ov = __shfl_xor(mv, off, 64);
        int oi = __shfl_xor(mi, off, 64);
        if (ov > mv || (ov == mv && oi < mi)) { mv = ov; mi = oi; }
      }
      topv[s] = mv;
      topi[s] = mi;
      if (l == mi) cur = -INFINITY;        // stable: lowest index wins ties
    }
    if (l == 0) {
      const int token = m0 + t;
      float x = Xs[t];
      float u = 1.f / (1.f + expf(-x));
      float kf = fmaf(3.f, u, 1.f);
      int kv = (int)rintf(kf);             // round-half-even == jnp.round
      kv = kv < 1 ? 1 : (kv > 4 ? 4 : kv);

      float wv[4];
#pragma unroll
      for (int s = 0; s < 4; ++s) wv[s] = (s < kv) ? topv[s] : 0.f;
      float mx = fmaxf(fmaxf(wv[0], wv[1]), fmaxf(wv[2], wv[3]));
      float e[4], sum = 0.f;
#pragma unroll
      for (int s = 0; s < 4; ++s) { e[s] = expf(wv[s] - mx); sum += e[s]; }
      float inv = 1.f / sum;
#pragma unroll
      for (int s = 0; s < 4; ++s) {
        out[(size_t)token * 4 + s] = e[s] * inv;
        out[Moff_i + (size_t)token * 4 + s] = (s < kv) ? (float)topi[s] : -1.0f;
      }
      out[Moff_k + token] = (float)kv;
    }
  }
}

extern "C" void kernel_launch(void* const* d_in, const int* in_sizes, int n_in,
                              void* d_out, int out_size, void* d_ws, size_t ws_size,
                              hipStream_t stream) {
  (void)n_in; (void)d_ws; (void)ws_size; (void)out_size;
  const float* hs  = (const float*)d_in[0];
  const float* Wr  = (const float*)d_in[1];
  const float* br  = (const float*)d_in[2];
  const float* Wu1 = (const float*)d_in[3];
  const float* bu1 = (const float*)d_in[4];
  const float* Wu2 = (const float*)d_in[5];
  const float* bu2 = (const float*)d_in[6];
  float* out = (float*)d_out;

  const int M = in_sizes[0] / DIM;  // 32768
  dim3 grid(M / BM);                // 512 blocks, 64 KB LDS, 2 blocks/CU
  dim3 block(512);                  // 8 waves -> 4 waves/SIMD
  hipLaunchKernelGGL(ur_hyb, grid, block, 0, stream,
                     hs, Wr, br, Wu1, bu1, Wu2, bu2, out, M);
}

// Round 18
// 230.430 us; speedup vs baseline: 6.9843x; 1.0617x over previous
//
#include <hip/hip_runtime.h>
#include <hip/hip_bf16.h>
#include <math.h>

#define DIM 1024
#define NE  64
#define BM  64
#define NT  32                    // 1024/32 k-tiles
// LDS: [2][A 8KB | Br 8KB] dbuf + Bu1 f32 32KB = 64KB
#define HALF_BYTES 16384
#define BU1_BASE   32768
#define LDS_BYTES  65536

typedef __attribute__((ext_vector_type(8))) short short8;
typedef __attribute__((ext_vector_type(4))) float f32x4;
typedef __attribute__((ext_vector_type(4))) unsigned uint4v;

__device__ __forceinline__ void gload16(const void* gptr, void* lptr) {
  __builtin_amdgcn_global_load_lds(
      (const __attribute__((address_space(1))) unsigned int*)(unsigned long long)gptr,
      (__attribute__((address_space(3))) unsigned int*)(unsigned int)(unsigned long long)lptr,
      16, 0, 0);
}

// Paired truncation 3-term bf16 split: f == h + m + l EXACTLY per value.
// Produces packed bf16-pair u32s (low16 = f0, high16 = f1) via v_perm_b32.
struct Sp3 { unsigned h, m, l; };
__device__ __forceinline__ Sp3 tsplit2(float f0, float f1) {
  Sp3 r;
  unsigned a = __float_as_uint(f0), b = __float_as_uint(f1);
  r.h = __builtin_amdgcn_perm(b, a, 0x07060302);   // [hi16(f1) | hi16(f0)]
  float r0 = f0 - __uint_as_float(a & 0xFFFF0000u);    // exact
  float r1 = f1 - __uint_as_float(b & 0xFFFF0000u);
  unsigned ra = __float_as_uint(r0), rb = __float_as_uint(r1);
  r.m = __builtin_amdgcn_perm(rb, ra, 0x07060302);
  float s0 = r0 - __uint_as_float(ra & 0xFFFF0000u);   // exact, fits bf16
  float s1 = r1 - __uint_as_float(rb & 0xFFFF0000u);
  r.l = __builtin_amdgcn_perm(__float_as_uint(s1), __float_as_uint(s0), 0x07060302);
  return r;
}

__device__ __forceinline__ short8 as_s8(uint4v v) {
  return *reinterpret_cast<short8*>(&v);
}

__global__ __launch_bounds__(512)
void ur_hyb(const float* __restrict__ hs,    // [M,1024]
            const float* __restrict__ Wr,    // [64,1024]
            const float* __restrict__ br,    // [64]
            const float* __restrict__ Wu1,   // [256,1024]
            const float* __restrict__ bu1,   // [256]
            const float* __restrict__ Wu2,   // [256]
            const float* __restrict__ bu2,   // [1]
            float* __restrict__ out,         // w[4M] | idx[4M] | k[M]
            int M) {
  __shared__ __align__(16) char smem[LDS_BYTES];

  const int tid = threadIdx.x;
  const int m0 = blockIdx.x * BM;
  const int w2 = tid >> 6, l = tid & 63;     // wave, lane
  const int g = l >> 4, c = l & 15;          // mfma fragment coords
  // router decomposition: 4 tokens x 2 cols per thread
  const int tg = tid >> 5;                   // 0..15 -> tokens 4tg..4tg+3
  const int rc = tid & 31;                   // cols rc, rc+32

  // ---- staging sources (R13-identical): LDS[row][q] = src[row][q ^ (row&7)] ----
  const int t8 = tid >> 3, k8 = tid & 7;
  const int kx = k8 ^ (t8 & 7);
  const char* pA  = (const char*)hs  + (size_t)(m0 + t8) * 4096 + (kx << 4);
  const char* pBr = (const char*)Wr  + (size_t)t8 * 4096 + (kx << 4);
  const char* pBu = (const char*)Wu1 + (size_t)t8 * 4096 + (kx << 4);
  const unsigned wb = (unsigned)(tid & ~63) * 16u;   // wave-uniform lane-0 part

  // fragment read offsets (R11-verified scheme; row&7 == c&7)
  const unsigned axk0 = (unsigned)(((2 * g) ^ (c & 7)) << 4);
  const unsigned axk1 = (unsigned)(((2 * g + 1) ^ (c & 7)) << 4);

  float ar[4][2];
#pragma unroll
  for (int j = 0; j < 4; ++j) { ar[j][0] = 0.f; ar[j][1] = 0.f; }
  f32x4 am_[4][2];
#pragma unroll
  for (int s = 0; s < 4; ++s)
#pragma unroll
    for (int n = 0; n < 2; ++n) am_[s][n] = (f32x4){0.f, 0.f, 0.f, 0.f};

  // ---- prologue: stage A/Br(0) into half 0 ----
  gload16(pA, smem + wb);
  gload16(pBr, smem + 8192 + wb);

  unsigned half = 0;
#pragma unroll 1
  for (int t = 0; t < NT; ++t) {
    // Bu1(t): 4 issues (prev readers done at last end-barrier)
#pragma unroll
    for (int li = 0; li < 4; ++li)
      gload16(pBu + (size_t)li * 262144, smem + (BU1_BASE + li * 8192 + wb));
    const unsigned oh = half ^ HALF_BYTES;
    if (t != NT - 1) { pA += 128; pBr += 128; pBu += 128; }
    gload16(pA, smem + oh + wb);
    gload16(pBr, smem + (oh + 8192 + wb));

    asm volatile("s_waitcnt vmcnt(6)" ::: "memory");  // A/Br(t) resident
    __builtin_amdgcn_s_barrier();

    // ---- phase 1: router fp32 VALU, 4 tok x 2 col ----
    const char* hb = smem + half;
#pragma unroll
    for (int kq = 0; kq < 8; ++kq) {
      f32x4 av[4];
#pragma unroll
      for (int j = 0; j < 4; ++j) {
        const int row = 4 * tg + j;
        av[j] = *reinterpret_cast<const f32x4*>(
            hb + row * 128 + (((unsigned)(kq ^ (row & 7))) << 4));
      }
#pragma unroll
      for (int n = 0; n < 2; ++n) {
        const int col = rc + 32 * n;
        const f32x4 bv = *reinterpret_cast<const f32x4*>(
            hb + 8192 + col * 128 + (((unsigned)(kq ^ (rc & 7))) << 4));
#pragma unroll
        for (int j = 0; j < 4; ++j) {
          ar[j][n] = fmaf(av[j][0], bv[0], ar[j][n]);
          ar[j][n] = fmaf(av[j][1], bv[1], ar[j][n]);
          ar[j][n] = fmaf(av[j][2], bv[2], ar[j][n]);
          ar[j][n] = fmaf(av[j][3], bv[3], ar[j][n]);
        }
      }
    }

    asm volatile("s_waitcnt vmcnt(2)" ::: "memory");   // Bu1(t) resident
    __builtin_amdgcn_s_barrier();

    // ---- phase 2: B splits (perm-packed), then per-s A split + 6-product MFMA ----
    short8 Bh[2], Bm[2], Bl[2];
#pragma unroll
    for (int n = 0; n < 2; ++n) {
      const char* bp = smem + BU1_BASE + w2 * 4096 + n * 2048 + c * 128;
      const f32x4 u0 = *reinterpret_cast<const f32x4*>(bp + axk0);
      const f32x4 u1v = *reinterpret_cast<const f32x4*>(bp + axk1);
      uint4v hv, mv, lv;
      Sp3 p0 = tsplit2(u0[0], u0[1]);
      Sp3 p1 = tsplit2(u0[2], u0[3]);
      Sp3 p2 = tsplit2(u1v[0], u1v[1]);
      Sp3 p3 = tsplit2(u1v[2], u1v[3]);
      hv[0] = p0.h; mv[0] = p0.m; lv[0] = p0.l;
      hv[1] = p1.h; mv[1] = p1.m; lv[1] = p1.l;
      hv[2] = p2.h; mv[2] = p2.m; lv[2] = p2.l;
      hv[3] = p3.h; mv[3] = p3.m; lv[3] = p3.l;
      Bh[n] = as_s8(hv); Bm[n] = as_s8(mv); Bl[n] = as_s8(lv);
    }
#pragma unroll
    for (int s = 0; s < 4; ++s) {
      const f32x4 v0 = *reinterpret_cast<const f32x4*>(hb + c * 128 + s * 2048 + axk0);
      const f32x4 v1 = *reinterpret_cast<const f32x4*>(hb + c * 128 + s * 2048 + axk1);
      uint4v hv, mv, lv;
      Sp3 p0 = tsplit2(v0[0], v0[1]);
      Sp3 p1 = tsplit2(v0[2], v0[3]);
      Sp3 p2 = tsplit2(v1[0], v1[1]);
      Sp3 p3 = tsplit2(v1[2], v1[3]);
      hv[0] = p0.h; mv[0] = p0.m; lv[0] = p0.l;
      hv[1] = p1.h; mv[1] = p1.m; lv[1] = p1.l;
      hv[2] = p2.h; mv[2] = p2.m; lv[2] = p2.l;
      hv[3] = p3.h; mv[3] = p3.m; lv[3] = p3.l;
      const short8 Ah = as_s8(hv), Am = as_s8(mv), Al = as_s8(lv);
#pragma unroll
      for (int n = 0; n < 2; ++n) {
        // 6 products (R11-proven set; drop ml/lm ~2^-24, ll ~2^-32)
        am_[s][n] = __builtin_amdgcn_mfma_f32_16x16x32_bf16(Al, Bh[n], am_[s][n], 0, 0, 0);
        am_[s][n] = __builtin_amdgcn_mfma_f32_16x16x32_bf16(Ah, Bl[n], am_[s][n], 0, 0, 0);
        am_[s][n] = __builtin_amdgcn_mfma_f32_16x16x32_bf16(Am, Bm[n], am_[s][n], 0, 0, 0);
        am_[s][n] = __builtin_amdgcn_mfma_f32_16x16x32_bf16(Am, Bh[n], am_[s][n], 0, 0, 0);
        am_[s][n] = __builtin_amdgcn_mfma_f32_16x16x32_bf16(Ah, Bm[n], am_[s][n], 0, 0, 0);
        am_[s][n] = __builtin_amdgcn_mfma_f32_16x16x32_bf16(Ah, Bh[n], am_[s][n], 0, 0, 0);
      }
    }

    __builtin_amdgcn_s_barrier();   // all readers of Bu1/half done
    half = oh;
  }
  __syncthreads();     // drains dangling loads; overlay safe

  // ---- epilogue ----
  float* Lg = reinterpret_cast<float*>(smem);                 // [64][65]
  float* Xp = reinterpret_cast<float*>(smem + 16640);         // [128][65]
  float* Xs = reinterpret_cast<float*>(smem + 49920);         // [64]

#pragma unroll
  for (int n = 0; n < 2; ++n) {
    const int col = rc + 32 * n;
    const float bias = br[col];
#pragma unroll
    for (int j = 0; j < 4; ++j) Lg[(4 * tg + j) * 65 + col] = ar[j][n] + bias;
  }

  // u1 -> GELU -> dot W_u2. C/D [m89, R11-verified]:
  // am_[s][n][reg] = h1[16s+4g+reg][32w2+16n+c]
  float xp[4][4];
#pragma unroll
  for (int s = 0; s < 4; ++s)
#pragma unroll
    for (int reg = 0; reg < 4; ++reg) xp[s][reg] = 0.f;
#pragma unroll
  for (int n = 0; n < 2; ++n) {
    const int qd = 32 * w2 + 16 * n + c;
    const float w2f = Wu2[qd];
    const float b1 = bu1[qd];
#pragma unroll
    for (int s = 0; s < 4; ++s)
#pragma unroll
      for (int reg = 0; reg < 4; ++reg) {
        float h = am_[s][n][reg] + b1;
        float ge = 0.5f * h * (1.f + erff(h * 0.70710678118654752440f));
        xp[s][reg] = fmaf(ge, w2f, xp[s][reg]);
      }
  }
#pragma unroll
  for (int s = 0; s < 4; ++s)
#pragma unroll
    for (int reg = 0; reg < 4; ++reg)
      Xp[(w2 * 16 + c) * 65 + 16 * s + 4 * g + reg] = xp[s][reg];
  __syncthreads();

  if (tid < BM) {
    float x = bu2[0];
#pragma unroll
    for (int cc = 0; cc < 128; ++cc) x += Xp[cc * 65 + tid];
    Xs[tid] = x;
  }
  __syncthreads();

  // ---- per-token top-4 + masked softmax: one wave per token ----
  const size_t Moff_i = 4 * (size_t)M;
  const size_t Moff_k = 8 * (size_t)M;

  for (int t = w2; t < BM; t += 8) {
    float cur = Lg[t * 65 + l];
    float topv[4];
    int topi[4];
#pragma unroll
    for (int s = 0; s < 4; ++s) {
      float mv = cur;
      int mi = l;
#pragma unroll
      for (int off = 32; off >= 1; off >>= 1) {
        float ov = __shfl_xor(mv, off, 64);
        int oi = __shfl_xor(mi, off, 64);
        if (ov > mv || (ov == mv && oi < mi)) { mv = ov; mi = oi; }
      }
      topv[s] = mv;
      topi[s] = mi;
      if (l == mi) cur = -INFINITY;        // stable: lowest index wins ties
    }
    if (l == 0) {
      const int token = m0 + t;
      float x = Xs[t];
      float u = 1.f / (1.f + expf(-x));
      float kf = fmaf(3.f, u, 1.f);
      int kv = (int)rintf(kf);             // round-half-even == jnp.round
      kv = kv < 1 ? 1 : (kv > 4 ? 4 : kv);

      float wv[4];
#pragma unroll
      for (int s = 0; s < 4; ++s) wv[s] = (s < kv) ? topv[s] : 0.f;
      float mx = fmaxf(fmaxf(wv[0], wv[1]), fmaxf(wv[2], wv[3]));
      float e[4], sum = 0.f;
#pragma unroll
      for (int s = 0; s < 4; ++s) { e[s] = expf(wv[s] - mx); sum += e[s]; }
      float inv = 1.f / sum;
#pragma unroll
      for (int s = 0; s < 4; ++s) {
        out[(size_t)token * 4 + s] = e[s] * inv;
        out[Moff_i + (size_t)token * 4 + s] = (s < kv) ? (float)topi[s] : -1.0f;
      }
      out[Moff_k + token] = (float)kv;
    }
  }
}

extern "C" void kernel_launch(void* const* d_in, const int* in_sizes, int n_in,
                              void* d_out, int out_size, void* d_ws, size_t ws_size,
                              hipStream_t stream) {
  (void)n_in; (void)d_ws; (void)ws_size; (void)out_size;
  const float* hs  = (const float*)d_in[0];
  const float* Wr  = (const float*)d_in[1];
  const float* br  = (const float*)d_in[2];
  const float* Wu1 = (const float*)d_in[3];
  const float* bu1 = (const float*)d_in[4];
  const float* Wu2 = (const float*)d_in[5];
  const float* bu2 = (const float*)d_in[6];
  float* out = (float*)d_out;

  const int M = in_sizes[0] / DIM;  // 32768
  dim3 grid(M / BM);                // 512 blocks, 64 KB LDS, 2 blocks/CU
  dim3 block(512);                  // 8 waves -> 4 waves/SIMD
  hipLaunchKernelGGL(ur_hyb, grid, block, 0, stream,
                     hs, Wr, br, Wu1, bu1, Wu2, bu2, out, M);
}